// Round 2
// baseline (213.398 us; speedup 1.0000x reference)
//
#include <hip/hip_runtime.h>
#include <hip/hip_bf16.h>

// TripletLoss N=8192, D=128. Round 4 (resubmit — prior bench hit GPU
// acquisition timeout): label-free O(N^2) main loop.
// Mining algebra: main pass accumulates UNMASKED negative-softmax sums
//   nl = sum_{j!=i} exp(-d_ij),  ns = sum_{j!=i} exp(-d_ij) * s_ij
// over ALL pairs (no label test, no positives, s = dist/sqrt2 units).
// A tiny per-label correction kernel (same-label pairs are only ~0.2%)
// subtracts the same-label mass from nl/ns and computes the positive
// sums pl/ps = sum exp(d-30)[*s] exactly, from the same bf16 rows.
// Self-pair (j==i) exclusion is confined to the single diagonal j-tile
// per block via template<DIAG>. exp folds both muls into one exp2 const.

typedef __bf16 bf16x8 __attribute__((ext_vector_type(8)));
typedef float f32x4 __attribute__((ext_vector_type(4)));

#define NROWS 8192
#define DIM 128
#define JTILE 64
#define LDS_STRIDE 136    // 128 + 8 bf16 pad: 272B = 17 x 16B units (odd -> b128 conflict-free)
#define NLABELS 512
#define GCAP 64           // max rows per label group (E[gsz]=16, P(gsz>64) ~ 0)
#define MARGIN_F 0.3f
#define SQRT2_F 1.41421356f
#define K1F (-2.04027892f)   // -sqrt2 * log2(e):  exp(-dist) = exp2(K1*s)
#define K2F ( 2.04027892f)   //  sqrt2 * log2(e)
#define C2F (-43.2808512f)   // -30 * log2(e):     exp(dist-30) = exp2(K2*s + C2)

// ---------------- kernel 1: bf16 cast + row norms + zero corr/gstat ----------
__global__ __launch_bounds__(256) void prep_kernel(const float* __restrict__ F,
                                                   __hip_bfloat16* __restrict__ Fb,
                                                   float* __restrict__ x2,
                                                   float4* __restrict__ corr,
                                                   float* __restrict__ gstat) {
    const int tid = threadIdx.x;
    const int wave = tid >> 6, lane = tid & 63;
    const int row = blockIdx.x * 4 + wave;
    float2 f = ((const float2*)(F + (size_t)row * DIM))[lane];
    ((__hip_bfloat162*)(Fb + (size_t)row * DIM))[lane] = __float22bfloat162_rn(f);
    float ss = f.x * f.x + f.y * f.y;
#pragma unroll
    for (int m = 32; m > 0; m >>= 1) ss += __shfl_xor(ss, m, 64);
    if (lane == 0) x2[row] = ss;
    const int g = blockIdx.x * 256 + tid;
    if (g < NROWS) corr[g] = make_float4(0.f, 0.f, 0.f, 0.f);
    if (blockIdx.x == 0 && tid < 4) gstat[tid] = 0.f;
}

// ---------------- kernel 2: fused GEMM + unmasked negative mining ----------
// C-operand init = -(x2i+x2j)/2 so acc[r] = dot - (x2i+x2j)/2 = -d2/2.
// DIAG instantiation zeroes the self-pair (dj == r) weight; only the one
// j-tile per block that overlaps the i-rows uses it.
template<bool DIAG>
__device__ __forceinline__ void tile_body(const __hip_bfloat16* __restrict__ sB,
                                          const float* __restrict__ sX2h,
                                          const bf16x8* a, const float* x2ih,
                                          float (&nl4)[4], float (&ns4)[4],
                                          int lm, int quad, int ig0, int jbase) {
#pragma unroll
    for (int jt = 0; jt < 4; ++jt) {
        const int jl = jt * 16 + lm;
        const __hip_bfloat16* bp = sB + jl * LDS_STRIDE + quad * 8;
        const float xjh = sX2h[jl];
        f32x4 acc;
#pragma unroll
        for (int r = 0; r < 4; ++r) acc[r] = x2ih[r] + xjh;
#pragma unroll
        for (int kc = 0; kc < 4; ++kc) {
            bf16x8 b = *(const bf16x8*)(bp + kc * 32);
            acc = __builtin_amdgcn_mfma_f32_16x16x32_bf16(a[kc], b, acc, 0, 0, 0);
        }
        const int dj = jbase + jl - ig0;   // self-pair iff dj == r
#pragma unroll
        for (int r = 0; r < 4; ++r) {
            float d2h = fmaxf(-acc[r], 5e-9f);          // = d2/2, clip(1e-8)
            float s = __builtin_amdgcn_sqrtf(d2h);      // dist = sqrt2 * s
            float ne = __builtin_amdgcn_exp2f(K1F * s); // exp(-dist)
            if (DIAG) ne = (dj == r) ? 0.f : ne;
            nl4[r] += ne;
            ns4[r] = fmaf(ne, s, ns4[r]);
        }
    }
}

__global__ __launch_bounds__(256, 8) void pairs_kernel(
        const __hip_bfloat16* __restrict__ Fb,
        const float* __restrict__ x2,
        float2* __restrict__ partial,
        int jspan) {
    __shared__ __hip_bfloat16 sB[JTILE * LDS_STRIDE];
    __shared__ float sX2h[JTILE];     // -0.5 * x2j

    const int tid = threadIdx.x;
    const int wave = tid >> 6;
    const int lane = tid & 63;
    const int quad = lane >> 4;
    const int lm = lane & 15;
    const int rbase = blockIdx.x * 64 + wave * 16;

    // A fragments (16 rows x K=128), kept for the whole j loop.
    bf16x8 a[4];
#pragma unroll
    for (int kc = 0; kc < 4; ++kc)
        a[kc] = *(const bf16x8*)(Fb + (size_t)(rbase + lm) * DIM + kc * 32 + quad * 8);

    // C/D layout: col(n)=lane&15 (j), row(m)=quad*4+r (i)
    const int ig0 = rbase + quad * 4;
    float x2ih[4];
#pragma unroll
    for (int r = 0; r < 4; ++r) x2ih[r] = -0.5f * x2[ig0 + r];

    float nl4[4] = {0,0,0,0}, ns4[4] = {0,0,0,0};

    const int j0 = blockIdx.y * jspan;
    const int jiters = jspan >> 6;
    const int djb = blockIdx.x - blockIdx.y * jiters;   // which jb holds the diagonal

    for (int jb = 0; jb < jiters; ++jb) {
        const int jbase = j0 + jb * JTILE;
        __syncthreads();   // protect LDS from previous iteration's readers
#pragma unroll
        for (int s = 0; s < 4; ++s) {
            int c = tid + s * 256;
            int jr = c >> 4, ck = c & 15;
            *(bf16x8*)(sB + jr * LDS_STRIDE + ck * 8) =
                *(const bf16x8*)(Fb + (size_t)(jbase + jr) * DIM + ck * 8);
        }
        if (tid < JTILE) sX2h[tid] = -0.5f * x2[jbase + tid];
        __syncthreads();

        if (jb == djb)
            tile_body<true >(sB, sX2h, a, x2ih, nl4, ns4, lm, quad, ig0, jbase);
        else
            tile_body<false>(sB, sX2h, a, x2ih, nl4, ns4, lm, quad, ig0, jbase);
    }

    // reduce over the 16 lanes (lm) sharing each i-row
#pragma unroll
    for (int m = 1; m < 16; m <<= 1) {
#pragma unroll
        for (int r = 0; r < 4; ++r) {
            nl4[r] += __shfl_xor(nl4[r], m, 64);
            ns4[r] += __shfl_xor(ns4[r], m, 64);
        }
    }
    if (lm == 0) {
#pragma unroll
        for (int r = 0; r < 4; ++r)
            partial[(size_t)blockIdx.y * NROWS + ig0 + r] =
                make_float2(nl4[r], ns4[r]);
    }
}

// ---------------- kernel 3: per-label correction + positives ----------------
// One wave per label. Collects the ~16 member rows (deterministic ballot
// order), then for each ordered same-label pair (a,b), b!=a, computes the
// bf16 dot (lane layout: b4=lane>>2 over 16 b's, cc=lane&3 over 32-dim
// chunks) and accumulates:  pl/ps (positives)  and  -nl/-ns (subtract the
// same-label mass the main pass added). One float4 store per row.
__global__ __launch_bounds__(64) void corr_kernel(
        const __hip_bfloat16* __restrict__ Fb,
        const float* __restrict__ x2,
        const int* __restrict__ labels,
        float4* __restrict__ corr) {
    const int L = blockIdx.x;
    const int lane = threadIdx.x;
    __shared__ int sIdx[GCAP];

    int cnt = 0;
    for (int c0 = 0; c0 < NROWS; c0 += 256) {
        int4 lv = *(const int4*)(labels + c0 + lane * 4);
#pragma unroll
        for (int k = 0; k < 4; ++k) {
            int labk = (k == 0) ? lv.x : (k == 1) ? lv.y : (k == 2) ? lv.z : lv.w;
            unsigned long long m = __ballot(labk == L);
            while (m) {
                int b = __builtin_ctzll(m);
                m &= m - 1;
                if (lane == 0 && cnt < GCAP) sIdx[cnt] = c0 + b * 4 + k;
                ++cnt;
            }
        }
    }
    const int gsz = cnt < GCAP ? cnt : GCAP;
    if (gsz == 0) return;
    __syncthreads();

    const int b4 = lane >> 2;    // b index within 16-chunk
    const int cc = lane & 3;     // 32-dim chunk

    for (int aI = 0; aI < gsz; ++aI) {
        const int ia = sIdx[aI];
        const __hip_bfloat16* pa = Fb + (size_t)ia * DIM + cc * 32;
        bf16x8 areg[4];
#pragma unroll
        for (int u = 0; u < 4; ++u) areg[u] = ((const bf16x8*)pa)[u];
        const float x2ha = 0.5f * x2[ia];

        float nl = 0.f, ns = 0.f, pl = 0.f, ps = 0.f;
        for (int bb = 0; bb < gsz; bb += 16) {
            const int b = bb + b4;
            const bool bv = (b < gsz) && (b != aI);
            const int ib = sIdx[b < gsz ? b : gsz - 1];
            const __hip_bfloat16* pb = Fb + (size_t)ib * DIM + cc * 32;
            float dot = 0.f;
#pragma unroll
            for (int u = 0; u < 4; ++u) {
                bf16x8 breg = ((const bf16x8*)pb)[u];
#pragma unroll
                for (int e = 0; e < 8; ++e)
                    dot = fmaf((float)areg[u][e], (float)breg[e], dot);
            }
            dot += __shfl_xor(dot, 1, 64);   // sum the 4 dim-chunks
            dot += __shfl_xor(dot, 2, 64);
            const float x2hb = 0.5f * x2[ib];
            float d2h = fmaxf(x2ha + x2hb - dot, 5e-9f);
            float s = __builtin_amdgcn_sqrtf(d2h);
            float ne = __builtin_amdgcn_exp2f(K1F * s);
            float pe = __builtin_amdgcn_exp2f(fmaf(K2F, s, C2F));
            if (bv && cc == 0) {
                nl += ne; ns = fmaf(ne, s, ns);
                pl += pe; ps = fmaf(pe, s, ps);
            }
        }
        // gather the 16 cc==0 lanes (xor masks 4..32 keep cc fixed)
#pragma unroll
        for (int m = 4; m < 64; m <<= 1) {
            nl += __shfl_xor(nl, m, 64);
            ns += __shfl_xor(ns, m, 64);
            pl += __shfl_xor(pl, m, 64);
            ps += __shfl_xor(ps, m, 64);
        }
        if (lane == 0) corr[ia] = make_float4(pl, ps, -nl, -ns);
    }
}

// ---------------- kernel 4: per-row loss + reduce + final divide ------------
__global__ __launch_bounds__(256) void finalize_kernel(const float2* __restrict__ partial,
                                                       const float4* __restrict__ corr,
                                                       float* __restrict__ gstat,
                                                       float* __restrict__ out,
                                                       int jsplit) {
    const int row = blockIdx.x * 256 + threadIdx.x;
    float4 c = corr[row];
    float nl = c.z, ns = c.w;    // negative corrections (subtract same-label mass)
    for (int s = 0; s < jsplit; ++s) {
        float2 p = partial[(size_t)s * NROWS + row];
        nl += p.x; ns += p.y;
    }
    float sum = 0.f, cnt = 0.f;
    if (c.x > 0.f && nl > 0.f) {
        float x = fmaf(SQRT2_F, c.y / c.x - ns / nl, MARGIN_F);  // wp - wn + margin
        sum = fmaxf(x, 0.f) + log1pf(__expf(-fabsf(x)));         // stable softplus
        cnt = 1.f;
    }
#pragma unroll
    for (int m = 32; m > 0; m >>= 1) {
        sum += __shfl_xor(sum, m, 64);
        cnt += __shfl_xor(cnt, m, 64);
    }
    __shared__ float sS[4], sC[4];
    const int wave = threadIdx.x >> 6, lane = threadIdx.x & 63;
    if (lane == 0) { sS[wave] = sum; sC[wave] = cnt; }
    __syncthreads();
    if (threadIdx.x == 0) {
        unsafeAtomicAdd(&gstat[0], sS[0] + sS[1] + sS[2] + sS[3]);
        unsafeAtomicAdd(&gstat[1], sC[0] + sC[1] + sC[2] + sC[3]);
        __threadfence();
        unsigned t = atomicAdd((unsigned int*)(gstat + 2), 1u);
        if (t == (unsigned)(gridDim.x - 1)) {
            float s2 = unsafeAtomicAdd(&gstat[0], 0.f);   // L2 reads
            float c2 = unsafeAtomicAdd(&gstat[1], 0.f);
            out[0] = s2 / fmaxf(c2, 1.f);
        }
    }
}

extern "C" void kernel_launch(void* const* d_in, const int* in_sizes, int n_in,
                              void* d_out, int out_size, void* d_ws, size_t ws_size,
                              hipStream_t stream) {
    const float* F = (const float*)d_in[0];
    const int* labels = (const int*)d_in[1];
    float* out = (float*)d_out;

    char* ws = (char*)d_ws;
    __hip_bfloat16* Fb = (__hip_bfloat16*)ws;                       // 2 MB
    size_t off = (size_t)NROWS * DIM * 2;
    float* x2 = (float*)(ws + off);  off += (size_t)NROWS * 4;      // 32 KB
    float4* corr = (float4*)(ws + off);  off += (size_t)NROWS * 16; // 128 KB

    int jsplit = 16;
    while (jsplit > 1 && off + (size_t)jsplit * NROWS * 8 + 16 > ws_size) jsplit >>= 1;
    float2* partial = (float2*)(ws + off);
    float* gstat = (float*)(ws + off + (size_t)jsplit * NROWS * 8);

    prep_kernel<<<NROWS / 4, 256, 0, stream>>>(F, Fb, x2, corr, gstat);
    pairs_kernel<<<dim3(NROWS / 64, jsplit), 256, 0, stream>>>(Fb, x2, labels ? partial : partial,
                                                               NROWS / jsplit);
    corr_kernel<<<NLABELS, 64, 0, stream>>>(Fb, x2, labels, corr);
    finalize_kernel<<<NROWS / 256, 256, 0, stream>>>(partial, corr, gstat, out, jsplit);
}

// Round 3
// 161.238 us; speedup vs baseline: 1.3235x; 1.3235x over previous
//
#include <hip/hip_runtime.h>
#include <hip/hip_bf16.h>

// TripletLoss N=8192, D=128. Round 5: round-4 structure (label-free O(N^2)
// main loop + per-label correction kernel) with the register-pressure fix.
// Round-4 post-mortem: __launch_bounds__(256,8) capped VGPRs at 32 and
// spilled the A-fragments + accumulators to scratch -> 235MB fetch / 82MB
// write of pure scratch traffic, 92us. Fix: (256,4) -> VGPR cap 128, zero
// spill, ~16 waves/CU (round-0 measured 44.7% occupancy at 6, same ballpark).
//
// Mining algebra: main pass accumulates UNMASKED negative-softmax sums
//   nl = sum_{j!=i} exp(-d_ij),  ns = sum_{j!=i} exp(-d_ij) * s_ij
// over ALL pairs (no label test, no positives, s = dist/sqrt2 units).
// A tiny per-label correction kernel (same-label pairs ~0.2%) subtracts the
// same-label mass from nl/ns and computes the positive sums pl/ps exactly,
// from the same bf16 rows. Self-pair exclusion confined to the single
// diagonal j-tile per block via template<DIAG>.

typedef __bf16 bf16x8 __attribute__((ext_vector_type(8)));
typedef float f32x4 __attribute__((ext_vector_type(4)));

#define NROWS 8192
#define DIM 128
#define JTILE 64
#define LDS_STRIDE 136    // 128 + 8 bf16 pad: 272B = 17 x 16B units (odd -> b128 conflict-free)
#define NLABELS 512
#define GCAP 64           // max rows per label group (E[gsz]=16, P(gsz>64) ~ 0)
#define MARGIN_F 0.3f
#define SQRT2_F 1.41421356f
#define K1F (-2.04027892f)   // -sqrt2 * log2(e):  exp(-dist) = exp2(K1*s)
#define K2F ( 2.04027892f)   //  sqrt2 * log2(e)
#define C2F (-43.2808512f)   // -30 * log2(e):     exp(dist-30) = exp2(K2*s + C2)

// ---------------- kernel 1: bf16 cast + row norms + zero corr/gstat ----------
__global__ __launch_bounds__(256) void prep_kernel(const float* __restrict__ F,
                                                   __hip_bfloat16* __restrict__ Fb,
                                                   float* __restrict__ x2,
                                                   float4* __restrict__ corr,
                                                   float* __restrict__ gstat) {
    const int tid = threadIdx.x;
    const int wave = tid >> 6, lane = tid & 63;
    const int row = blockIdx.x * 4 + wave;
    float2 f = ((const float2*)(F + (size_t)row * DIM))[lane];
    ((__hip_bfloat162*)(Fb + (size_t)row * DIM))[lane] = __float22bfloat162_rn(f);
    float ss = f.x * f.x + f.y * f.y;
#pragma unroll
    for (int m = 32; m > 0; m >>= 1) ss += __shfl_xor(ss, m, 64);
    if (lane == 0) x2[row] = ss;
    const int g = blockIdx.x * 256 + tid;
    if (g < NROWS) corr[g] = make_float4(0.f, 0.f, 0.f, 0.f);
    if (blockIdx.x == 0 && tid < 4) gstat[tid] = 0.f;
}

// ---------------- kernel 2: fused GEMM + unmasked negative mining ----------
// C-operand init = -(x2i+x2j)/2 so acc[r] = dot - (x2i+x2j)/2 = -d2/2.
// DIAG instantiation zeroes the self-pair (dj == r) weight; only the one
// j-tile per block that overlaps the i-rows uses it.
template<bool DIAG>
__device__ __forceinline__ void tile_body(const __hip_bfloat16* __restrict__ sB,
                                          const float* __restrict__ sX2h,
                                          const bf16x8* a, const float* x2ih,
                                          float (&nl4)[4], float (&ns4)[4],
                                          int lm, int quad, int ig0, int jbase) {
#pragma unroll
    for (int jt = 0; jt < 4; ++jt) {
        const int jl = jt * 16 + lm;
        const __hip_bfloat16* bp = sB + jl * LDS_STRIDE + quad * 8;
        const float xjh = sX2h[jl];
        f32x4 acc;
#pragma unroll
        for (int r = 0; r < 4; ++r) acc[r] = x2ih[r] + xjh;
#pragma unroll
        for (int kc = 0; kc < 4; ++kc) {
            bf16x8 b = *(const bf16x8*)(bp + kc * 32);
            acc = __builtin_amdgcn_mfma_f32_16x16x32_bf16(a[kc], b, acc, 0, 0, 0);
        }
        const int dj = jbase + jl - ig0;   // self-pair iff dj == r
#pragma unroll
        for (int r = 0; r < 4; ++r) {
            float d2h = fmaxf(-acc[r], 5e-9f);          // = d2/2, clip(1e-8)
            float s = __builtin_amdgcn_sqrtf(d2h);      // dist = sqrt2 * s
            float ne = __builtin_amdgcn_exp2f(K1F * s); // exp(-dist)
            if (DIAG) ne = (dj == r) ? 0.f : ne;
            nl4[r] += ne;
            ns4[r] = fmaf(ne, s, ns4[r]);
        }
    }
}

__global__ __launch_bounds__(256, 4) void pairs_kernel(
        const __hip_bfloat16* __restrict__ Fb,
        const float* __restrict__ x2,
        float2* __restrict__ partial,
        int jspan) {
    __shared__ __hip_bfloat16 sB[JTILE * LDS_STRIDE];
    __shared__ float sX2h[JTILE];     // -0.5 * x2j

    const int tid = threadIdx.x;
    const int wave = tid >> 6;
    const int lane = tid & 63;
    const int quad = lane >> 4;
    const int lm = lane & 15;
    const int rbase = blockIdx.x * 64 + wave * 16;

    // A fragments (16 rows x K=128), kept for the whole j loop.
    bf16x8 a[4];
#pragma unroll
    for (int kc = 0; kc < 4; ++kc)
        a[kc] = *(const bf16x8*)(Fb + (size_t)(rbase + lm) * DIM + kc * 32 + quad * 8);

    // C/D layout: col(n)=lane&15 (j), row(m)=quad*4+r (i)
    const int ig0 = rbase + quad * 4;
    float x2ih[4];
#pragma unroll
    for (int r = 0; r < 4; ++r) x2ih[r] = -0.5f * x2[ig0 + r];

    float nl4[4] = {0,0,0,0}, ns4[4] = {0,0,0,0};

    const int j0 = blockIdx.y * jspan;
    const int jiters = jspan >> 6;
    const int djb = blockIdx.x - blockIdx.y * jiters;   // which jb holds the diagonal

    for (int jb = 0; jb < jiters; ++jb) {
        const int jbase = j0 + jb * JTILE;
        __syncthreads();   // protect LDS from previous iteration's readers
#pragma unroll
        for (int s = 0; s < 4; ++s) {
            int c = tid + s * 256;
            int jr = c >> 4, ck = c & 15;
            *(bf16x8*)(sB + jr * LDS_STRIDE + ck * 8) =
                *(const bf16x8*)(Fb + (size_t)(jbase + jr) * DIM + ck * 8);
        }
        if (tid < JTILE) sX2h[tid] = -0.5f * x2[jbase + tid];
        __syncthreads();

        if (jb == djb)
            tile_body<true >(sB, sX2h, a, x2ih, nl4, ns4, lm, quad, ig0, jbase);
        else
            tile_body<false>(sB, sX2h, a, x2ih, nl4, ns4, lm, quad, ig0, jbase);
    }

    // reduce over the 16 lanes (lm) sharing each i-row
#pragma unroll
    for (int m = 1; m < 16; m <<= 1) {
#pragma unroll
        for (int r = 0; r < 4; ++r) {
            nl4[r] += __shfl_xor(nl4[r], m, 64);
            ns4[r] += __shfl_xor(ns4[r], m, 64);
        }
    }
    if (lm == 0) {
#pragma unroll
        for (int r = 0; r < 4; ++r)
            partial[(size_t)blockIdx.y * NROWS + ig0 + r] =
                make_float2(nl4[r], ns4[r]);
    }
}

// ---------------- kernel 3: per-label correction + positives ----------------
// One wave per label. Collects the ~16 member rows (deterministic ballot
// order), then for each ordered same-label pair (a,b), b!=a, computes the
// bf16 dot (lane layout: b4=lane>>2 over 16 b's, cc=lane&3 over 32-dim
// chunks) and accumulates:  pl/ps (positives)  and  -nl/-ns (subtract the
// same-label mass the main pass added). One float4 store per row.
__global__ __launch_bounds__(64) void corr_kernel(
        const __hip_bfloat16* __restrict__ Fb,
        const float* __restrict__ x2,
        const int* __restrict__ labels,
        float4* __restrict__ corr) {
    const int L = blockIdx.x;
    const int lane = threadIdx.x;
    __shared__ int sIdx[GCAP];

    int cnt = 0;
    for (int c0 = 0; c0 < NROWS; c0 += 256) {
        int4 lv = *(const int4*)(labels + c0 + lane * 4);
#pragma unroll
        for (int k = 0; k < 4; ++k) {
            int labk = (k == 0) ? lv.x : (k == 1) ? lv.y : (k == 2) ? lv.z : lv.w;
            unsigned long long m = __ballot(labk == L);
            while (m) {
                int b = __builtin_ctzll(m);
                m &= m - 1;
                if (lane == 0 && cnt < GCAP) sIdx[cnt] = c0 + b * 4 + k;
                ++cnt;
            }
        }
    }
    const int gsz = cnt < GCAP ? cnt : GCAP;
    if (gsz == 0) return;
    __syncthreads();

    const int b4 = lane >> 2;    // b index within 16-chunk
    const int cc = lane & 3;     // 32-dim chunk

    for (int aI = 0; aI < gsz; ++aI) {
        const int ia = sIdx[aI];
        const __hip_bfloat16* pa = Fb + (size_t)ia * DIM + cc * 32;
        bf16x8 areg[4];
#pragma unroll
        for (int u = 0; u < 4; ++u) areg[u] = ((const bf16x8*)pa)[u];
        const float x2ha = 0.5f * x2[ia];

        float nl = 0.f, ns = 0.f, pl = 0.f, ps = 0.f;
        for (int bb = 0; bb < gsz; bb += 16) {
            const int b = bb + b4;
            const bool bv = (b < gsz) && (b != aI);
            const int ib = sIdx[b < gsz ? b : gsz - 1];
            const __hip_bfloat16* pb = Fb + (size_t)ib * DIM + cc * 32;
            float dot = 0.f;
#pragma unroll
            for (int u = 0; u < 4; ++u) {
                bf16x8 breg = ((const bf16x8*)pb)[u];
#pragma unroll
                for (int e = 0; e < 8; ++e)
                    dot = fmaf((float)areg[u][e], (float)breg[e], dot);
            }
            dot += __shfl_xor(dot, 1, 64);   // sum the 4 dim-chunks
            dot += __shfl_xor(dot, 2, 64);
            const float x2hb = 0.5f * x2[ib];
            float d2h = fmaxf(x2ha + x2hb - dot, 5e-9f);
            float s = __builtin_amdgcn_sqrtf(d2h);
            float ne = __builtin_amdgcn_exp2f(K1F * s);
            float pe = __builtin_amdgcn_exp2f(fmaf(K2F, s, C2F));
            if (bv && cc == 0) {
                nl += ne; ns = fmaf(ne, s, ns);
                pl += pe; ps = fmaf(pe, s, ps);
            }
        }
        // gather the 16 cc==0 lanes (xor masks 4..32 keep cc fixed)
#pragma unroll
        for (int m = 4; m < 64; m <<= 1) {
            nl += __shfl_xor(nl, m, 64);
            ns += __shfl_xor(ns, m, 64);
            pl += __shfl_xor(pl, m, 64);
            ps += __shfl_xor(ps, m, 64);
        }
        if (lane == 0) corr[ia] = make_float4(pl, ps, -nl, -ns);
    }
}

// ---------------- kernel 4: per-row loss + reduce + final divide ------------
__global__ __launch_bounds__(256) void finalize_kernel(const float2* __restrict__ partial,
                                                       const float4* __restrict__ corr,
                                                       float* __restrict__ gstat,
                                                       float* __restrict__ out,
                                                       int jsplit) {
    const int row = blockIdx.x * 256 + threadIdx.x;
    float4 c = corr[row];
    float nl = c.z, ns = c.w;    // negative corrections (subtract same-label mass)
    for (int s = 0; s < jsplit; ++s) {
        float2 p = partial[(size_t)s * NROWS + row];
        nl += p.x; ns += p.y;
    }
    float sum = 0.f, cnt = 0.f;
    if (c.x > 0.f && nl > 0.f) {
        float x = fmaf(SQRT2_F, c.y / c.x - ns / nl, MARGIN_F);  // wp - wn + margin
        sum = fmaxf(x, 0.f) + log1pf(__expf(-fabsf(x)));         // stable softplus
        cnt = 1.f;
    }
#pragma unroll
    for (int m = 32; m > 0; m >>= 1) {
        sum += __shfl_xor(sum, m, 64);
        cnt += __shfl_xor(cnt, m, 64);
    }
    __shared__ float sS[4], sC[4];
    const int wave = threadIdx.x >> 6, lane = threadIdx.x & 63;
    if (lane == 0) { sS[wave] = sum; sC[wave] = cnt; }
    __syncthreads();
    if (threadIdx.x == 0) {
        unsafeAtomicAdd(&gstat[0], sS[0] + sS[1] + sS[2] + sS[3]);
        unsafeAtomicAdd(&gstat[1], sC[0] + sC[1] + sC[2] + sC[3]);
        __threadfence();
        unsigned t = atomicAdd((unsigned int*)(gstat + 2), 1u);
        if (t == (unsigned)(gridDim.x - 1)) {
            float s2 = unsafeAtomicAdd(&gstat[0], 0.f);   // L2 reads
            float c2 = unsafeAtomicAdd(&gstat[1], 0.f);
            out[0] = s2 / fmaxf(c2, 1.f);
        }
    }
}

extern "C" void kernel_launch(void* const* d_in, const int* in_sizes, int n_in,
                              void* d_out, int out_size, void* d_ws, size_t ws_size,
                              hipStream_t stream) {
    const float* F = (const float*)d_in[0];
    const int* labels = (const int*)d_in[1];
    float* out = (float*)d_out;

    char* ws = (char*)d_ws;
    __hip_bfloat16* Fb = (__hip_bfloat16*)ws;                       // 2 MB
    size_t off = (size_t)NROWS * DIM * 2;
    float* x2 = (float*)(ws + off);  off += (size_t)NROWS * 4;      // 32 KB
    float4* corr = (float4*)(ws + off);  off += (size_t)NROWS * 16; // 128 KB

    int jsplit = 16;
    while (jsplit > 1 && off + (size_t)jsplit * NROWS * 8 + 16 > ws_size) jsplit >>= 1;
    float2* partial = (float2*)(ws + off);
    float* gstat = (float*)(ws + off + (size_t)jsplit * NROWS * 8);

    prep_kernel<<<NROWS / 4, 256, 0, stream>>>(F, Fb, x2, corr, gstat);
    pairs_kernel<<<dim3(NROWS / 64, jsplit), 256, 0, stream>>>(Fb, x2, partial,
                                                               NROWS / jsplit);
    corr_kernel<<<NLABELS, 64, 0, stream>>>(Fb, x2, labels, corr);
    finalize_kernel<<<NROWS / 256, 256, 0, stream>>>(partial, corr, gstat, out, jsplit);
}